// Round 4
// baseline (270.002 us; speedup 1.0000x reference)
//
#include <hip/hip_runtime.h>
#include <hip/hip_cooperative_groups.h>
#include <math.h>

namespace cg = cooperative_groups;

// GraphPyramidPooling, single cooperative kernel. Adjacency g is dead code.
// Node-centric math: per node i,
//   s0=sig(h.W0+b0), z1=s0*(h.W1), s1=sig(z1+b1), z2=s0*s1*(h.W2), s2=sig(z2+b2)
// Level-0 rank: (s0 desc, i asc).  Level-1 rank (among sel0): (z1 desc, cnt0 asc).
// Level-2 rank (among sel1): (z2 desc, r1 asc).  sigma strictly monotone (fp64)
// => ranking z == ranking sigma(z); tie keys are previous-level ranks (distinct ints).
// Output (verified semantics, matches round-3 kernel which passed):
//   out[i]       = h[i]*gateA[i]                      gateA = sel0 ? s0 : 0
//   out[cnt0[g]] += h[g]*(r1[g]<K1 ? s0*s1 : 0)       rows cover [0,K0) bijectively
//   out[r1[g]]   += h[g]*(r2[g]<K2 ? s0*s1*s2 : 0)    rows cover [0,K1) bijectively
//
// Static: N0=4096, D=512; K0=int(.8*4096)=3276, K1=int(.6*3276)=1965, K2=int(.4*1965)=786

#define N0 4096
#define K0 3276
#define K1 1965
#define K2 786
#define DD 512
#define NB 256
#define NT 256
#define BIGR (1 << 30)

struct GppArgs {
    const float* h; const float* W; const float* b;
    float* out;
    double* k0; double* k1; double* k2;      // rank keys per node
    float* gA; float* gB; float* gC;         // gate products per node
    int* cnt0; int* r1;                      // per-node ranks (lvl0, lvl1)
    float* gateA;                            // per-row gates / sources for scatter
    int* srcB; float* gateBv;
    int* srcC; float* gateCv;
};

__device__ __forceinline__ double dsig(double z) { return 1.0 / (1.0 + exp(-z)); }

__launch_bounds__(NT, 1)
__global__ void gpp_fused(GppArgs a) {
    cg::grid_group grid = cg::this_grid();
    __shared__ double s_d[N0];   // 32 KB: staged rank keys
    __shared__ int    s_i[N0];   // 16 KB: staged tie/sel keys
    const int tid = (int)threadIdx.x;
    const int bid = (int)blockIdx.x;
    const int gid = bid * NT + tid;

    // ---------- P1: dots (16 lanes per row; fp64 accumulate) ----------
    {
        int row = gid >> 4;
        int l   = gid & 15;
        const float4* hr = (const float4*)(a.h + (size_t)row * DD);
        const float4* w0 = (const float4*)(a.W);
        const float4* w1 = (const float4*)(a.W + DD);
        const float4* w2 = (const float4*)(a.W + 2 * DD);
        double a0 = 0.0, a1 = 0.0, a2 = 0.0;
#pragma unroll
        for (int k = 0; k < 8; ++k) {
            int q = (k << 4) + l;              // 16 lanes read contiguous float4s
            float4 hv = hr[q];
            float4 v0 = w0[q], v1 = w1[q], v2 = w2[q];
            a0 += (double)hv.x * v0.x + (double)hv.y * v0.y +
                  (double)hv.z * v0.z + (double)hv.w * v0.w;
            a1 += (double)hv.x * v1.x + (double)hv.y * v1.y +
                  (double)hv.z * v1.z + (double)hv.w * v1.w;
            a2 += (double)hv.x * v2.x + (double)hv.y * v2.y +
                  (double)hv.z * v2.z + (double)hv.w * v2.w;
        }
#pragma unroll
        for (int m = 8; m >= 1; m >>= 1) {
            a0 += __shfl_xor(a0, m, 16);
            a1 += __shfl_xor(a1, m, 16);
            a2 += __shfl_xor(a2, m, 16);
        }
        if (l == 0) {
            double s0 = dsig(a0 + (double)a.b[0]);
            double z1 = s0 * a1;
            double s1 = dsig(z1 + (double)a.b[1]);
            double z2 = s1 * s0 * a2;
            double s2 = dsig(z2 + (double)a.b[2]);
            a.k0[row] = s0;
            a.k1[row] = z1;
            a.k2[row] = z2;
            a.gA[row] = (float)s0;
            a.gB[row] = (float)(s0 * s1);
            a.gC[row] = (float)(s0 * s1 * s2);
        }
    }
    grid.sync();

    // ---------- P2: rank0 = #{j : s0[j]>s0[i] or (==, j<i)} ----------
    {
        for (int k = tid; k < N0; k += NT) s_d[k] = a.k0[k];
        __syncthreads();
        int i  = (bid << 4) + (tid >> 4);
        int jj = tid & 15;
        double ki = s_d[i];
        int c = 0;
#pragma unroll 8
        for (int k = 0; k < N0 / 16; ++k) {
            int j = jj + (k << 4);
            double kj = s_d[j];
            c += (int)((kj > ki) | ((kj == ki) & (j < i)));
        }
        c += __shfl_xor(c, 1, 16); c += __shfl_xor(c, 2, 16);
        c += __shfl_xor(c, 4, 16); c += __shfl_xor(c, 8, 16);
        if (jj == 0) a.cnt0[i] = c;
    }
    grid.sync();

    // ---------- P3: rank1 among sel0 by (z1 desc, cnt0 asc) ----------
    {
        for (int k = tid; k < N0; k += NT) { s_d[k] = a.k1[k]; s_i[k] = a.cnt0[k]; }
        __syncthreads();
        int i  = (bid << 4) + (tid >> 4);
        int jj = tid & 15;
        double ki = s_d[i];
        int ti = s_i[i];
        int c = 0;
#pragma unroll 8
        for (int k = 0; k < N0 / 16; ++k) {
            int j = jj + (k << 4);
            double kj = s_d[j];
            int tj = s_i[j];
            c += (int)((tj < K0) & ((kj > ki) | ((kj == ki) & (tj < ti))));
        }
        c += __shfl_xor(c, 1, 16); c += __shfl_xor(c, 2, 16);
        c += __shfl_xor(c, 4, 16); c += __shfl_xor(c, 8, 16);
        if (jj == 0) a.r1[i] = (ti < K0) ? c : BIGR;
    }
    grid.sync();

    // ---------- P4: rank2 among sel1 by (z2 desc, r1 asc) + finalize ----------
    {
        for (int k = tid; k < N0; k += NT) { s_d[k] = a.k2[k]; s_i[k] = a.r1[k]; }
        __syncthreads();
        int i  = (bid << 4) + (tid >> 4);
        int jj = tid & 15;
        double ki = s_d[i];
        int ri = s_i[i];
        int c = 0;
#pragma unroll 8
        for (int k = 0; k < N0 / 16; ++k) {
            int j = jj + (k << 4);
            double kj = s_d[j];
            int tj = s_i[j];
            c += (int)((tj < K1) & ((kj > ki) | ((kj == ki) & (tj < ri))));
        }
        c += __shfl_xor(c, 1, 16); c += __shfl_xor(c, 2, 16);
        c += __shfl_xor(c, 4, 16); c += __shfl_xor(c, 8, 16);
        if (jj == 0) {
            int r2 = (ri < K1) ? c : BIGR;
            int c0 = a.cnt0[i];
            a.gateA[i] = (c0 < K0) ? a.gA[i] : 0.0f;
            if (c0 < K0) {                      // rows cover [0,K0) exactly once
                a.srcB[c0]   = i;
                a.gateBv[c0] = (ri < K1) ? a.gB[i] : 0.0f;
            }
            if (ri < K1) {                      // rows cover [0,K1) exactly once
                a.srcC[ri]   = i;
                a.gateCv[ri] = (r2 < K2) ? a.gC[i] : 0.0f;
            }
        }
    }
    grid.sync();

    // ---------- P5: write-only scatter, out = sum of up to 3 gated rows ----------
    {
        const float4* h4 = (const float4*)a.h;
        float4* o4 = (float4*)a.out;
        int t = gid & 127;              // 128 float4 per row
        int rbase = gid >> 7;           // 0..511
#pragma unroll
        for (int it = 0; it < 8; ++it) {
            int row = rbase + (it << 9);
            float ga = a.gateA[row];
            float4 v = h4[(size_t)row * 128 + t];
            float4 o;
            o.x = v.x * ga; o.y = v.y * ga; o.z = v.z * ga; o.w = v.w * ga;
            if (row < K0) {
                int s = a.srcB[row]; float gb = a.gateBv[row];
                float4 vb = h4[(size_t)s * 128 + t];
                o.x += vb.x * gb; o.y += vb.y * gb; o.z += vb.z * gb; o.w += vb.w * gb;
            }
            if (row < K1) {
                int s = a.srcC[row]; float gc = a.gateCv[row];
                float4 vc = h4[(size_t)s * 128 + t];
                o.x += vc.x * gc; o.y += vc.y * gc; o.z += vc.z * gc; o.w += vc.w * gc;
            }
            o4[(size_t)row * 128 + t] = o;
        }
    }
}

extern "C" void kernel_launch(void* const* d_in, const int* in_sizes, int n_in,
                              void* d_out, int out_size, void* d_ws, size_t ws_size,
                              hipStream_t stream) {
    (void)in_sizes; (void)n_in; (void)out_size; (void)ws_size;
    char* ws = (char*)d_ws;

    GppArgs a;
    a.h   = (const float*)d_in[1];   // d_in[0] = g, unused (dead code)
    a.W   = (const float*)d_in[2];
    a.b   = (const float*)d_in[3];
    a.out = (float*)d_out;
    a.k0     = (double*)(ws + 0);         // 32 KB
    a.k1     = (double*)(ws + 32768);     // 32 KB
    a.k2     = (double*)(ws + 65536);     // 32 KB
    a.gA     = (float*)(ws + 98304);      // 16 KB
    a.gB     = (float*)(ws + 114688);
    a.gC     = (float*)(ws + 131072);
    a.cnt0   = (int*)(ws + 147456);
    a.r1     = (int*)(ws + 163840);
    a.gateA  = (float*)(ws + 180224);
    a.srcB   = (int*)(ws + 196608);
    a.gateBv = (float*)(ws + 212992);
    a.srcC   = (int*)(ws + 229376);
    a.gateCv = (float*)(ws + 245760);     // ends at 256 KB

    void* params[] = { &a };
    hipLaunchCooperativeKernel((const void*)gpp_fused, dim3(NB), dim3(NT),
                               params, 0, stream);
}

// Round 5
// 145.278 us; speedup vs baseline: 1.8585x; 1.8585x over previous
//
#include <hip/hip_runtime.h>
#include <math.h>

// GraphPyramidPooling — 5-kernel pipeline (adjacency g is dead code w.r.t. output).
// Round-4's verified phase logic split at the grid.sync points: in-kernel
// grid.sync() on 8-XCD gfx950 costs ~35-40us each (cross-XCD L2 coherence),
// while kernel boundaries are ~2us and give the same ordering for free.
//
// Node-centric math: per node i,
//   s0=sig(h.W0+b0), z1=s0*(h.W1), s1=sig(z1+b1), z2=s0*s1*(h.W2), s2=sig(z2+b2)
// Rank0: (s0 desc, i asc). Rank1 among sel0: (z1 desc, cnt0 asc).
// Rank2 among sel1: (z2 desc, r1 asc). sigma strictly monotone in fp64 =>
// ranking z == ranking sigma(z); tie keys are previous-level ranks (distinct).
// Output:
//   out[i]     = h[i]*gateA[i]                    gateA = sel0 ? s0 : 0
//   out[c0[g]] += h[g]*(r1[g]<K1 ? s0*s1 : 0)     rows cover [0,K0) bijectively
//   out[r1[g]] += h[g]*(r2[g]<K2 ? s0*s1*s2 : 0)  rows cover [0,K1) bijectively
//
// Static: N0=4096, D=512; K0=int(.8*4096)=3276, K1=int(.6*3276)=1965, K2=int(.4*1965)=786

#define N0 4096
#define K0 3276
#define K1 1965
#define K2 786
#define DD 512
#define BIGR (1 << 30)

__device__ __forceinline__ double dsig(double z) { return 1.0 / (1.0 + exp(-z)); }

// ---- K1: dots. 16 lanes per row; fp64 accumulate; emits keys + gate products ----
__global__ void gpp_dots(const float* __restrict__ h, const float* __restrict__ W,
                         const float* __restrict__ b,
                         double* __restrict__ k0, double* __restrict__ k1,
                         double* __restrict__ k2, float* __restrict__ gA,
                         float* __restrict__ gB, float* __restrict__ gC) {
    int gid = (int)(blockIdx.x * blockDim.x + threadIdx.x);
    int row = gid >> 4;
    int l   = gid & 15;
    const float4* hr = (const float4*)(h + (size_t)row * DD);
    const float4* w0 = (const float4*)(W);
    const float4* w1 = (const float4*)(W + DD);
    const float4* w2 = (const float4*)(W + 2 * DD);
    double a0 = 0.0, a1 = 0.0, a2 = 0.0;
#pragma unroll
    for (int k = 0; k < 8; ++k) {
        int q = (k << 4) + l;
        float4 hv = hr[q];
        float4 v0 = w0[q], v1 = w1[q], v2 = w2[q];
        a0 += (double)hv.x * v0.x + (double)hv.y * v0.y +
              (double)hv.z * v0.z + (double)hv.w * v0.w;
        a1 += (double)hv.x * v1.x + (double)hv.y * v1.y +
              (double)hv.z * v1.z + (double)hv.w * v1.w;
        a2 += (double)hv.x * v2.x + (double)hv.y * v2.y +
              (double)hv.z * v2.z + (double)hv.w * v2.w;
    }
#pragma unroll
    for (int m = 8; m >= 1; m >>= 1) {
        a0 += __shfl_xor(a0, m, 16);
        a1 += __shfl_xor(a1, m, 16);
        a2 += __shfl_xor(a2, m, 16);
    }
    if (l == 0) {
        double s0 = dsig(a0 + (double)b[0]);
        double z1 = s0 * a1;
        double s1 = dsig(z1 + (double)b[1]);
        double z2 = s1 * s0 * a2;
        double s2 = dsig(z2 + (double)b[2]);
        k0[row] = s0;
        k1[row] = z1;
        k2[row] = z2;
        gA[row] = (float)s0;
        gB[row] = (float)(s0 * s1);
        gC[row] = (float)(s0 * s1 * s2);
    }
}

// ---- K2: rank0 + gateA. Block bid covers rows [bid*16, bid*16+16) ----
__global__ void gpp_rank0(const double* __restrict__ k0, const float* __restrict__ gA,
                          int* __restrict__ cnt0, float* __restrict__ gateA) {
    __shared__ double s_d[N0];
    int tid = (int)threadIdx.x;
    for (int k = tid; k < N0; k += 256) s_d[k] = k0[k];
    __syncthreads();
    int i  = ((int)blockIdx.x << 4) + (tid >> 4);
    int jj = tid & 15;
    double ki = s_d[i];
    int c = 0;
#pragma unroll 8
    for (int k = 0; k < N0 / 16; ++k) {
        int j = jj + (k << 4);
        double kj = s_d[j];
        c += (int)((kj > ki) | ((kj == ki) & (j < i)));
    }
    c += __shfl_xor(c, 1, 16); c += __shfl_xor(c, 2, 16);
    c += __shfl_xor(c, 4, 16); c += __shfl_xor(c, 8, 16);
    if (jj == 0) {
        cnt0[i] = c;
        gateA[i] = (c < K0) ? gA[i] : 0.0f;
    }
}

// ---- K3: rank1 among sel0 + srcB/gateBv (scatter by cnt0, bijective on [0,K0)) ----
__global__ void gpp_rank1(const double* __restrict__ k1, const int* __restrict__ cnt0,
                          const float* __restrict__ gB, int* __restrict__ r1,
                          int* __restrict__ srcB, float* __restrict__ gateBv) {
    __shared__ double s_d[N0];
    __shared__ int    s_i[N0];
    int tid = (int)threadIdx.x;
    for (int k = tid; k < N0; k += 256) { s_d[k] = k1[k]; s_i[k] = cnt0[k]; }
    __syncthreads();
    int i  = ((int)blockIdx.x << 4) + (tid >> 4);
    int jj = tid & 15;
    double ki = s_d[i];
    int ti = s_i[i];
    int c = 0;
#pragma unroll 8
    for (int k = 0; k < N0 / 16; ++k) {
        int j = jj + (k << 4);
        double kj = s_d[j];
        int tj = s_i[j];
        c += (int)((tj < K0) & ((kj > ki) | ((kj == ki) & (tj < ti))));
    }
    c += __shfl_xor(c, 1, 16); c += __shfl_xor(c, 2, 16);
    c += __shfl_xor(c, 4, 16); c += __shfl_xor(c, 8, 16);
    if (jj == 0) {
        int rv = (ti < K0) ? c : BIGR;
        r1[i] = rv;
        if (ti < K0) {
            srcB[ti]   = i;
            gateBv[ti] = (rv < K1) ? gB[i] : 0.0f;
        }
    }
}

// ---- K4: rank2 among sel1 + srcC/gateCv (scatter by r1, bijective on [0,K1)) ----
__global__ void gpp_rank2(const double* __restrict__ k2, const int* __restrict__ r1,
                          const float* __restrict__ gC,
                          int* __restrict__ srcC, float* __restrict__ gateCv) {
    __shared__ double s_d[N0];
    __shared__ int    s_i[N0];
    int tid = (int)threadIdx.x;
    for (int k = tid; k < N0; k += 256) { s_d[k] = k2[k]; s_i[k] = r1[k]; }
    __syncthreads();
    int i  = ((int)blockIdx.x << 4) + (tid >> 4);
    int jj = tid & 15;
    double ki = s_d[i];
    int ri = s_i[i];
    int c = 0;
#pragma unroll 8
    for (int k = 0; k < N0 / 16; ++k) {
        int j = jj + (k << 4);
        double kj = s_d[j];
        int tj = s_i[j];
        c += (int)((tj < K1) & ((kj > ki) | ((kj == ki) & (tj < ri))));
    }
    c += __shfl_xor(c, 1, 16); c += __shfl_xor(c, 2, 16);
    c += __shfl_xor(c, 4, 16); c += __shfl_xor(c, 8, 16);
    if (jj == 0 && ri < K1) {
        srcC[ri]   = i;
        gateCv[ri] = (c < K2) ? gC[i] : 0.0f;
    }
}

// ---- K5: write-only scatter; one block per output row ----
__global__ void gpp_scatter(const float* __restrict__ h, const float* __restrict__ gateA,
                            const int* __restrict__ srcB, const float* __restrict__ gateBv,
                            const int* __restrict__ srcC, const float* __restrict__ gateCv,
                            float* __restrict__ out) {
    int row = (int)blockIdx.x;
    int t = (int)threadIdx.x;  // 128 threads * float4 = 512 floats
    const float4* h4 = (const float4*)h;
    float ga = gateA[row];
    float4 v = h4[(size_t)row * 128 + t];
    float4 o;
    o.x = v.x * ga; o.y = v.y * ga; o.z = v.z * ga; o.w = v.w * ga;
    if (row < K0) {
        int s = srcB[row]; float gb = gateBv[row];
        float4 vb = h4[(size_t)s * 128 + t];
        o.x += vb.x * gb; o.y += vb.y * gb; o.z += vb.z * gb; o.w += vb.w * gb;
    }
    if (row < K1) {
        int s = srcC[row]; float gc = gateCv[row];
        float4 vc = h4[(size_t)s * 128 + t];
        o.x += vc.x * gc; o.y += vc.y * gc; o.z += vc.z * gc; o.w += vc.w * gc;
    }
    ((float4*)out)[(size_t)row * 128 + t] = o;
}

extern "C" void kernel_launch(void* const* d_in, const int* in_sizes, int n_in,
                              void* d_out, int out_size, void* d_ws, size_t ws_size,
                              hipStream_t stream) {
    (void)in_sizes; (void)n_in; (void)out_size; (void)ws_size;
    const float* h = (const float*)d_in[1];   // d_in[0] = g, unused (dead code)
    const float* W = (const float*)d_in[2];
    const float* b = (const float*)d_in[3];
    float* out = (float*)d_out;

    char* ws = (char*)d_ws;
    double* k0     = (double*)(ws + 0);         // 32 KB
    double* k1     = (double*)(ws + 32768);     // 32 KB
    double* k2     = (double*)(ws + 65536);     // 32 KB
    float*  gA     = (float*)(ws + 98304);      // 16 KB each below
    float*  gB     = (float*)(ws + 114688);
    float*  gC     = (float*)(ws + 131072);
    int*    cnt0   = (int*)(ws + 147456);
    int*    r1     = (int*)(ws + 163840);
    float*  gateA  = (float*)(ws + 180224);
    int*    srcB   = (int*)(ws + 196608);
    float*  gateBv = (float*)(ws + 212992);
    int*    srcC   = (int*)(ws + 229376);
    float*  gateCv = (float*)(ws + 245760);     // ends at 256 KB

    gpp_dots<<<256, 256, 0, stream>>>(h, W, b, k0, k1, k2, gA, gB, gC);
    gpp_rank0<<<256, 256, 0, stream>>>(k0, gA, cnt0, gateA);
    gpp_rank1<<<256, 256, 0, stream>>>(k1, cnt0, gB, r1, srcB, gateBv);
    gpp_rank2<<<256, 256, 0, stream>>>(k2, r1, gC, srcC, gateCv);
    gpp_scatter<<<N0, 128, 0, stream>>>(h, gateA, srcB, gateBv, srcC, gateCv, out);
}